// Round 1
// baseline (216.401 us; speedup 1.0000x reference)
//
#include <hip/hip_runtime.h>
#include <hip/hip_bf16.h>

typedef __attribute__((ext_vector_type(8))) __bf16 bf16x8;
typedef __attribute__((ext_vector_type(4))) float f32x4;

#define MFMA(a, b, c) __builtin_amdgcn_mfma_f32_16x16x32_bf16((a), (b), (c), 0, 0, 0)

// load 8 consecutive f32 and convert to bf16x8 A/B fragment
__device__ __forceinline__ bf16x8 cvt8(const float* __restrict__ p) {
    const f32x4 a = *(const f32x4*)(p);
    const f32x4 b = *(const f32x4*)(p + 4);
    bf16x8 r;
    r[0] = (__bf16)a[0]; r[1] = (__bf16)a[1]; r[2] = (__bf16)a[2]; r[3] = (__bf16)a[3];
    r[4] = (__bf16)b[0]; r[5] = (__bf16)b[1]; r[6] = (__bf16)b[2]; r[7] = (__bf16)b[3];
    return r;
}

// ---------------------------------------------------------------------------
// Kernel 1: y1 = x @ W1a[0:128,:] + b1a ;  y2 = x @ W2a[0:128,:] + b2a
// (bias baked in; used as MFMA C-init by the edge / node kernels)
// ---------------------------------------------------------------------------
__global__ __launch_bounds__(256) void precompute_y(
    const float* __restrict__ x,
    const float* __restrict__ W1a, const float* __restrict__ b1a,
    const float* __restrict__ W2a, const float* __restrict__ b2a,
    float* __restrict__ y1, float* __restrict__ y2,
    int N, int ntiles)
{
    const int LDK = 136;                       // 128 + 8 pad (bank-conflict break)
    __shared__ __align__(16) __bf16 w1t[64 * 136];
    __shared__ __align__(16) __bf16 w2t[64 * 136];
    for (int idx = threadIdx.x; idx < 64 * 128; idx += 256) {
        int k = idx >> 6, n = idx & 63;
        w1t[n * LDK + k] = (__bf16)W1a[k * 64 + n];
        w2t[n * LDK + k] = (__bf16)W2a[k * 64 + n];
    }
    __syncthreads();

    const int lane = threadIdx.x & 63, wave = threadIdx.x >> 6;
    const int l15 = lane & 15, l4 = lane >> 4;

    float bias1[4], bias2[4];
#pragma unroll
    for (int nt = 0; nt < 4; ++nt) {
        bias1[nt] = b1a[l15 + 16 * nt];
        bias2[nt] = b2a[l15 + 16 * nt];
    }

    for (int tile = blockIdx.x * 4 + wave; tile < ntiles; tile += gridDim.x * 4) {
        const int rbase = tile * 16;
        const int arow = min(rbase + l15, N - 1);
        f32x4 acc1[4], acc2[4];
#pragma unroll
        for (int nt = 0; nt < 4; ++nt) {
            acc1[nt] = (f32x4){0.f, 0.f, 0.f, 0.f};
            acc2[nt] = (f32x4){0.f, 0.f, 0.f, 0.f};
        }
#pragma unroll
        for (int j = 0; j < 4; ++j) {
            const int k0 = j * 32 + l4 * 8;
            bf16x8 a = cvt8(x + (size_t)arow * 128 + k0);
#pragma unroll
            for (int nt = 0; nt < 4; ++nt) {
                bf16x8 b1 = *(const bf16x8*)(w1t + (l15 + 16 * nt) * LDK + k0);
                acc1[nt] = MFMA(a, b1, acc1[nt]);
                bf16x8 b2 = *(const bf16x8*)(w2t + (l15 + 16 * nt) * LDK + k0);
                acc2[nt] = MFMA(a, b2, acc2[nt]);
            }
        }
#pragma unroll
        for (int nt = 0; nt < 4; ++nt) {
            const int col = l15 + 16 * nt;
#pragma unroll
            for (int r = 0; r < 4; ++r) {
                const int row = rbase + l4 * 4 + r;
                if (row < N) {
                    y1[(size_t)row * 64 + col] = acc1[nt][r] + bias1[nt];
                    y2[(size_t)row * 64 + col] = acc2[nt][r] + bias2[nt];
                }
            }
        }
    }
}

// ---------------------------------------------------------------------------
// Kernel 2: per-edge  pre1 = y1[send] + eattr @ W1a[128:192,:]
//           msg = relu( relu(pre1) @ W1b + b1b )
//           atomicAdd(agg[recv], msg)
// ---------------------------------------------------------------------------
__global__ __launch_bounds__(256) void edge_pass(
    const float* __restrict__ eattr,
    const int* __restrict__ send, const int* __restrict__ recv,
    const float* __restrict__ W1a, const float* __restrict__ W1b,
    const float* __restrict__ b1b,
    const float* __restrict__ y1, float* __restrict__ agg,
    int E, int ntiles)
{
    const int LDK = 72;                        // 64 + 8 pad
    __shared__ __align__(16) __bf16 wat[64 * 72];   // W1a[128:192,:]^T
    __shared__ __align__(16) __bf16 wbt[64 * 72];   // W1b^T
    __shared__ __align__(16) __bf16 hbuf[4][16 * 72];
    for (int idx = threadIdx.x; idx < 64 * 64; idx += 256) {
        int k = idx >> 6, n = idx & 63;
        wat[n * LDK + k] = (__bf16)W1a[(128 + k) * 64 + n];
        wbt[n * LDK + k] = (__bf16)W1b[k * 64 + n];
    }
    __syncthreads();

    const int lane = threadIdx.x & 63, wave = threadIdx.x >> 6;
    const int l15 = lane & 15, l4 = lane >> 4;
    __bf16* hb = hbuf[wave];

    float biasb[4];
#pragma unroll
    for (int nt = 0; nt < 4; ++nt) biasb[nt] = b1b[l15 + 16 * nt];

    for (int tile = blockIdx.x * 4 + wave; tile < ntiles; tile += gridDim.x * 4) {
        const int ebase = tile * 16;

        // ---- layer 1: C-init = gathered y1[send[e]], A = edge_attr, B = W1a_e^T
        f32x4 acc[4];
        int rcv[4];
#pragma unroll
        for (int r = 0; r < 4; ++r) {
            const int e = min(ebase + l4 * 4 + r, E - 1);
            const int s = send[e];
            rcv[r] = recv[e];
            const float* yp = y1 + (size_t)s * 64 + l15;
#pragma unroll
            for (int nt = 0; nt < 4; ++nt) acc[nt][r] = yp[16 * nt];
        }
        const int arow = min(ebase + l15, E - 1);
#pragma unroll
        for (int j = 0; j < 2; ++j) {
            const int k0 = j * 32 + l4 * 8;
            bf16x8 a = cvt8(eattr + (size_t)arow * 64 + k0);
#pragma unroll
            for (int nt = 0; nt < 4; ++nt) {
                bf16x8 b = *(const bf16x8*)(wat + (l15 + 16 * nt) * LDK + k0);
                acc[nt] = MFMA(a, b, acc[nt]);
            }
        }
        // relu -> stage h tile (bf16) in per-wave LDS for the layer-2 A operand
#pragma unroll
        for (int nt = 0; nt < 4; ++nt)
#pragma unroll
            for (int r = 0; r < 4; ++r)
                hb[(l4 * 4 + r) * LDK + (l15 + 16 * nt)] = (__bf16)fmaxf(acc[nt][r], 0.f);

        // ---- layer 2: A = h (LDS), B = W1b^T, C-init = b1b
        f32x4 acc2[4];
#pragma unroll
        for (int nt = 0; nt < 4; ++nt)
            acc2[nt] = (f32x4){biasb[nt], biasb[nt], biasb[nt], biasb[nt]};
#pragma unroll
        for (int j = 0; j < 2; ++j) {
            const int k0 = j * 32 + l4 * 8;
            bf16x8 a = *(const bf16x8*)(hb + l15 * LDK + k0);
#pragma unroll
            for (int nt = 0; nt < 4; ++nt) {
                bf16x8 b = *(const bf16x8*)(wbt + (l15 + 16 * nt) * LDK + k0);
                acc2[nt] = MFMA(a, b, acc2[nt]);
            }
        }
        // relu + scatter-add
#pragma unroll
        for (int nt = 0; nt < 4; ++nt) {
            const int col = l15 + 16 * nt;
#pragma unroll
            for (int r = 0; r < 4; ++r) {
                const int e = ebase + l4 * 4 + r;
                if (e < E)
                    atomicAdd(agg + (size_t)rcv[r] * 64 + col, fmaxf(acc2[nt][r], 0.f));
            }
        }
    }
}

// ---------------------------------------------------------------------------
// Kernel 3: per-node  pre = y2[n] + agg[n] @ W2a[128:192,:]
//           out = relu( relu(pre) @ W2b + b2b )
// ---------------------------------------------------------------------------
__global__ __launch_bounds__(256) void node_pass(
    const float* __restrict__ agg,
    const float* __restrict__ W2a, const float* __restrict__ W2b,
    const float* __restrict__ b2b,
    const float* __restrict__ y2, float* __restrict__ out,
    int N, int ntiles)
{
    const int LDK = 72;
    __shared__ __align__(16) __bf16 wat[64 * 72];   // W2a[128:192,:]^T
    __shared__ __align__(16) __bf16 wbt[64 * 72];   // W2b^T
    __shared__ __align__(16) __bf16 hbuf[4][16 * 72];
    for (int idx = threadIdx.x; idx < 64 * 64; idx += 256) {
        int k = idx >> 6, n = idx & 63;
        wat[n * LDK + k] = (__bf16)W2a[(128 + k) * 64 + n];
        wbt[n * LDK + k] = (__bf16)W2b[k * 64 + n];
    }
    __syncthreads();

    const int lane = threadIdx.x & 63, wave = threadIdx.x >> 6;
    const int l15 = lane & 15, l4 = lane >> 4;
    __bf16* hb = hbuf[wave];

    float biasb[4];
#pragma unroll
    for (int nt = 0; nt < 4; ++nt) biasb[nt] = b2b[l15 + 16 * nt];

    for (int tile = blockIdx.x * 4 + wave; tile < ntiles; tile += gridDim.x * 4) {
        const int rbase = tile * 16;

        f32x4 acc[4];
#pragma unroll
        for (int r = 0; r < 4; ++r) {
            const int row = min(rbase + l4 * 4 + r, N - 1);
            const float* yp = y2 + (size_t)row * 64 + l15;
#pragma unroll
            for (int nt = 0; nt < 4; ++nt) acc[nt][r] = yp[16 * nt];
        }
        const int arow = min(rbase + l15, N - 1);
#pragma unroll
        for (int j = 0; j < 2; ++j) {
            const int k0 = j * 32 + l4 * 8;
            bf16x8 a = cvt8(agg + (size_t)arow * 64 + k0);
#pragma unroll
            for (int nt = 0; nt < 4; ++nt) {
                bf16x8 b = *(const bf16x8*)(wat + (l15 + 16 * nt) * LDK + k0);
                acc[nt] = MFMA(a, b, acc[nt]);
            }
        }
#pragma unroll
        for (int nt = 0; nt < 4; ++nt)
#pragma unroll
            for (int r = 0; r < 4; ++r)
                hb[(l4 * 4 + r) * LDK + (l15 + 16 * nt)] = (__bf16)fmaxf(acc[nt][r], 0.f);

        f32x4 acc2[4];
#pragma unroll
        for (int nt = 0; nt < 4; ++nt)
            acc2[nt] = (f32x4){biasb[nt], biasb[nt], biasb[nt], biasb[nt]};
#pragma unroll
        for (int j = 0; j < 2; ++j) {
            const int k0 = j * 32 + l4 * 8;
            bf16x8 a = *(const bf16x8*)(hb + l15 * LDK + k0);
#pragma unroll
            for (int nt = 0; nt < 4; ++nt) {
                bf16x8 b = *(const bf16x8*)(wbt + (l15 + 16 * nt) * LDK + k0);
                acc2[nt] = MFMA(a, b, acc2[nt]);
            }
        }
#pragma unroll
        for (int nt = 0; nt < 4; ++nt) {
            const int col = l15 + 16 * nt;
#pragma unroll
            for (int r = 0; r < 4; ++r) {
                const int row = rbase + l4 * 4 + r;
                if (row < N)
                    out[(size_t)row * 64 + col] = fmaxf(acc2[nt][r], 0.f);
            }
        }
    }
}

// ---------------------------------------------------------------------------
extern "C" void kernel_launch(void* const* d_in, const int* in_sizes, int n_in,
                              void* d_out, int out_size, void* d_ws, size_t ws_size,
                              hipStream_t stream) {
    const float* x     = (const float*)d_in[0];
    const int*   eidx  = (const int*)d_in[1];
    const float* eattr = (const float*)d_in[2];
    // d_in[3] = u (unused), d_in[4] = batch (unused)
    const float* W1a = (const float*)d_in[5];
    const float* b1a = (const float*)d_in[6];
    const float* W1b = (const float*)d_in[7];
    const float* b1b = (const float*)d_in[8];
    const float* W2a = (const float*)d_in[9];
    const float* b2a = (const float*)d_in[10];
    const float* W2b = (const float*)d_in[11];
    const float* b2b = (const float*)d_in[12];
    float* out = (float*)d_out;

    const int N = in_sizes[0] / 128;
    const int E = in_sizes[1] / 2;
    const int* send = eidx;         // edge_index[0,:]
    const int* recv = eidx + E;     // edge_index[1,:]

    float* agg = (float*)d_ws;
    float* y1  = agg + (size_t)N * 64;
    float* y2  = y1 + (size_t)N * 64;

    hipMemsetAsync(agg, 0, (size_t)N * 64 * sizeof(float), stream);

    const int ntilesN = (N + 15) / 16;
    const int ntilesE = (E + 15) / 16;
    const int blkN = (ntilesN + 3) / 4;
    int blkE = (ntilesE + 3) / 4;
    if (blkE > 2048) blkE = 2048;

    precompute_y<<<blkN, 256, 0, stream>>>(x, W1a, b1a, W2a, b2a, y1, y2, N, ntilesN);
    edge_pass<<<blkE, 256, 0, stream>>>(eattr, send, recv, W1a, W1b, b1b, y1, agg, E, ntilesE);
    node_pass<<<blkN, 256, 0, stream>>>(agg, W2a, W2b, b2b, y2, out, N, ntilesN);
}